// Round 10
// baseline (208.976 us; speedup 1.0000x reference)
//
#include <hip/hip_runtime.h>
#include <hip/hip_bf16.h>

#define NNODES 50000
#define NEDGES 800000
#define D 128
#define DOUT 64
#define SCAN_BLOCKS 196   // 196*256 = 50176 >= NNODES
#define NPB 16            // nodes per block in fused gather1+gemm2

// binned CSR build
#define BSHIFT 7
#define BMASK 127
#define NBUCK 391         // ceil(50000/128)
#define BCAP 2560         // bucket capacity (mean 2048, sigma~45 -> >11 sigma)
#define CH 2048           // edges per bin block

// y1 is stored slice-major: y1s[4][NNODES][32] bf16 (each slice 3.2MB -> L2-resident)
#define SLICE_STRIDE (NNODES * 32)

typedef unsigned short ushort8 __attribute__((ext_vector_type(8)));
typedef short bf16x8 __attribute__((ext_vector_type(8)));
typedef float f32x4 __attribute__((ext_vector_type(4)));

__device__ inline unsigned short f32_to_bf16(float f) {
    unsigned u = __float_as_uint(f);
    u = (u + 0x7fffu + ((u >> 16) & 1u)) >> 16;   // round-to-nearest-even
    return (unsigned short)u;
}

// ---------------------------------------------------------------------------
// waT[c][k] = bf16((Wpre @ W1)[k][c]);  ba = bpre @ W1 + b1 (f32)
__global__ void combine_w_kernel(const float* __restrict__ Wpre, const float* __restrict__ bpre,
                                 const float* __restrict__ W1, const float* __restrict__ b1,
                                 unsigned short* __restrict__ waT, float* __restrict__ ba) {
    const int j = threadIdx.x;
    const int i = blockIdx.x;
    if (i < D) {
        float s = 0.0f;
        for (int k = 0; k < D; ++k) s = fmaf(Wpre[i * D + k], W1[k * D + j], s);
        waT[j * D + i] = f32_to_bf16(s);     // transposed store
    } else {
        float s = b1[j];
        for (int k = 0; k < D; ++k) s = fmaf(bpre[k], W1[k * D + j], s);
        ba[j] = s;
    }
}

// --- binned CSR build ------------------------------------------------------
// bcursor[b] holds the COUNT in bucket b (zeroed by memset each launch).
__global__ void bin_kernel(const int* __restrict__ ei, int* __restrict__ bcursor,
                           unsigned int* __restrict__ bins) {
    __shared__ int cnt[NBUCK];
    __shared__ int base[NBUCK];
    const int tid = threadIdx.x;
    const int e0 = blockIdx.x * CH;

    for (int i = tid; i < NBUCK; i += 256) cnt[i] = 0;
    __syncthreads();

    int src[8], dstl[8], nb[8];
    #pragma unroll
    for (int i = 0; i < 8; ++i) {
        const int e = e0 + i * 256 + tid;
        if (e < NEDGES) {
            src[i] = ei[e];
            const int d = ei[NEDGES + e];
            dstl[i] = d & BMASK;
            nb[i] = d >> BSHIFT;
        } else {
            nb[i] = -1;
        }
    }
    #pragma unroll
    for (int i = 0; i < 8; ++i)
        if (nb[i] >= 0) atomicAdd(&cnt[nb[i]], 1);
    __syncthreads();

    for (int b = tid; b < NBUCK; b += 256) {
        base[b] = (cnt[b] > 0) ? (b * BCAP + atomicAdd(&bcursor[b], cnt[b])) : 0;
        cnt[b] = 0;   // reuse as local offset
    }
    __syncthreads();

    #pragma unroll
    for (int i = 0; i < 8; ++i) {
        if (nb[i] >= 0) {
            const int off = atomicAdd(&cnt[nb[i]], 1);
            const int pos = base[nb[i]] + off;
            if (pos < (nb[i] + 1) * BCAP)
                bins[pos] = ((unsigned)src[i] << BSHIFT) | (unsigned)dstl[i];
        }
    }
}

// per-bucket histogram -> deg written coalesced (covers all i < NBUCK*128)
__global__ void count_kernel(const unsigned int* __restrict__ bins,
                             const int* __restrict__ bcursor, int* __restrict__ deg) {
    __shared__ int cnt[128];
    const int b = blockIdx.x;
    const int tid = threadIdx.x;
    if (tid < 128) cnt[tid] = 0;
    __syncthreads();
    int n = bcursor[b];
    if (n > BCAP) n = BCAP;
    const unsigned int* p = bins + (size_t)b * BCAP;
    for (int i = tid; i < n; i += 256) atomicAdd(&cnt[p[i] & BMASK], 1);
    __syncthreads();
    if (tid < 128) deg[b * 128 + tid] = cnt[tid];
}

// --- hierarchical exclusive scan of deg -> rowstart ------------------------
__global__ void scan_part1(const int* __restrict__ deg, int* __restrict__ excl,
                           int* __restrict__ partials) {
    __shared__ int sm[256];
    const int t = threadIdx.x;
    const int i = blockIdx.x * 256 + t;
    const int v = (i < NNODES) ? deg[i] : 0;
    sm[t] = v;
    __syncthreads();
    #pragma unroll
    for (int off = 1; off < 256; off <<= 1) {
        const int cur = sm[t];
        const int add = (t >= off) ? sm[t - off] : 0;
        __syncthreads();
        sm[t] = cur + add;
        __syncthreads();
    }
    excl[i] = sm[t] - v;
    if (t == 255) partials[blockIdx.x] = sm[255];
}

// merged part2+part3: every block re-scans the 196 partials (cheap), then adds base
__global__ void scan_part3(const int* __restrict__ excl, const int* __restrict__ partials,
                           int* __restrict__ rowstart) {
    __shared__ int sm[256];
    const int t = threadIdx.x;
    const int v = (t < SCAN_BLOCKS) ? partials[t] : 0;
    sm[t] = v;
    __syncthreads();
    #pragma unroll
    for (int off = 1; off < 256; off <<= 1) {
        const int cur = sm[t];
        const int add = (t >= off) ? sm[t - off] : 0;
        __syncthreads();
        sm[t] = cur + add;
        __syncthreads();
    }
    const int b = blockIdx.x;
    const int base = (b == 0) ? 0 : sm[b - 1];
    const int i = b * 256 + t;
    if (i < NNODES) rowstart[i] = base + excl[i];
    if (b == 0 && t == 0) rowstart[NNODES] = NEDGES;
}

// per-bucket placement: scatter within a ~4KB ebuf window
__global__ void place_kernel(const unsigned int* __restrict__ bins,
                             const int* __restrict__ bcursor,
                             const int* __restrict__ rowstart,
                             unsigned short* __restrict__ ebuf) {
    __shared__ int lcur[128];
    const int b = blockIdx.x;
    const int tid = threadIdx.x;
    if (tid < 128) {
        const int node = b * 128 + tid;
        lcur[tid] = (node < NNODES) ? rowstart[node] : 0;
    }
    __syncthreads();
    int n = bcursor[b];
    if (n > BCAP) n = BCAP;
    const unsigned int* p = bins + (size_t)b * BCAP;
    for (int i = tid; i < n; i += 256) {
        const unsigned v = p[i];
        const int pos = atomicAdd(&lcur[v & BMASK], 1);
        ebuf[pos] = (unsigned short)(v >> BSHIFT);
    }
}

// ---------------------------------------------------------------------------
// y1s = bf16(x @ Wa) via MFMA, stored slice-major [4][N][32].
__global__ void __launch_bounds__(256) gemm_y1_mfma(const float* __restrict__ x,
                                                    const unsigned short* __restrict__ waT,
                                                    unsigned short* __restrict__ y1s) {
    __shared__ unsigned short xs[64][136];
    __shared__ unsigned short wsm[128][136];
    const int tid = threadIdx.x;
    const int rbase = blockIdx.x * 64;

    #pragma unroll
    for (int i = 0; i < 8; ++i) {
        const int f = tid + i * 256;
        const int r = f >> 4;              // 0..127
        const int c8 = f & 15;
        *(ushort8*)&wsm[r][c8 * 8] = *(const ushort8*)&waT[r * D + c8 * 8];
    }
    #pragma unroll
    for (int i = 0; i < 4; ++i) {
        const int f = tid + i * 256;
        const int r = f >> 4;              // 0..63
        const int c8 = f & 15;
        int rg = rbase + r;
        if (rg > NNODES - 1) rg = NNODES - 1;
        const float4 v0 = *(const float4*)&x[(size_t)rg * D + c8 * 8];
        const float4 v1 = *(const float4*)&x[(size_t)rg * D + c8 * 8 + 4];
        ushort8 o;
        o[0] = f32_to_bf16(v0.x); o[1] = f32_to_bf16(v0.y);
        o[2] = f32_to_bf16(v0.z); o[3] = f32_to_bf16(v0.w);
        o[4] = f32_to_bf16(v1.x); o[5] = f32_to_bf16(v1.y);
        o[6] = f32_to_bf16(v1.z); o[7] = f32_to_bf16(v1.w);
        *(ushort8*)&xs[r][c8 * 8] = o;
    }
    __syncthreads();

    const int lane = tid & 63;
    const int wv = tid >> 6;          // wave -> rows wv*16..+15
    const int r16 = lane & 15;
    const int kg = lane >> 4;         // 0..3

    f32x4 acc[8];
    #pragma unroll
    for (int ct = 0; ct < 8; ++ct) acc[ct] = (f32x4){0.f, 0.f, 0.f, 0.f};

    #pragma unroll
    for (int kq = 0; kq < 4; ++kq) {
        const int ko = kq * 32 + kg * 8;
        const bf16x8 a = *(const bf16x8*)&xs[wv * 16 + r16][ko];
        #pragma unroll
        for (int ct = 0; ct < 8; ++ct) {
            const bf16x8 b = *(const bf16x8*)&wsm[ct * 16 + r16][ko];
            acc[ct] = __builtin_amdgcn_mfma_f32_16x16x32_bf16(a, b, acc[ct], 0, 0, 0);
        }
    }

    #pragma unroll
    for (int ct = 0; ct < 8; ++ct) {
        const int col = ct * 16 + r16;
        const int sl = col >> 5, wi = col & 31;
        #pragma unroll
        for (int reg = 0; reg < 4; ++reg) {
            const int row = rbase + wv * 16 + kg * 4 + reg;
            if (row < NNODES)
                y1s[(size_t)sl * SLICE_STRIDE + (size_t)row * 32 + wi] = f32_to_bf16(acc[ct][reg]);
        }
    }
}

// ---------------------------------------------------------------------------
#define ACC8(q)                                                        \
    do {                                                               \
        a[0] += __uint_as_float((q).x << 16);                          \
        a[1] += __uint_as_float((q).x & 0xffff0000u);                  \
        a[2] += __uint_as_float((q).y << 16);                          \
        a[3] += __uint_as_float((q).y & 0xffff0000u);                  \
        a[4] += __uint_as_float((q).z << 16);                          \
        a[5] += __uint_as_float((q).z & 0xffff0000u);                  \
        a[6] += __uint_as_float((q).w << 16);                          \
        a[7] += __uint_as_float((q).w & 0xffff0000u);                  \
    } while (0)

// Fused: h1 = relu(mean_agg(y1)+ba) -> LDS (f32); y2 = bf16(h1 @ W2)
// Phase 1 is column-sliced: per slice (3.2MB, L2-resident), 16 lanes/node split
// as 4 edge-groups x 4 col-quarters; __shfl_xor(4/8) reduces edge-groups.
__global__ void gather1_gemm2_kernel(const unsigned short* __restrict__ y1s,
                                     const int* __restrict__ rowstart,
                                     const unsigned short* __restrict__ ebuf,
                                     const float* __restrict__ ba,
                                     const float* __restrict__ W2,
                                     unsigned short* __restrict__ y2) {
    __shared__ float h1s[NPB][132];   // phase-2 reads are nloc-broadcast: conflict-free
    __shared__ float w2s[16][132];    // float4 reads: 2-way aliasing = free (m136)
    const int tid = threadIdx.x;
    const int nloc = tid >> 4;        // 0..15
    const int sub = tid & 15;         // 0..15
    const int g = sub >> 2;           // edge group 0..3
    const int c = sub & 3;            // column quarter 0..3
    const int node = blockIdx.x * NPB + nloc;

    const int beg = rowstart[node];
    const int cnt = rowstart[node + 1] - beg;
    const unsigned short* nb = ebuf + beg;
    const float inv = 1.0f / (float)(cnt + 1);

    #pragma unroll
    for (int s = 0; s < 4; ++s) {
        const unsigned short* tab = y1s + (size_t)s * SLICE_STRIDE;
        float a[8];
        if (g == 0) {   // self loop counted once
            const uint4 q = *(const uint4*)&tab[(size_t)node * 32 + c * 8];
            a[0] = __uint_as_float(q.x << 16);  a[1] = __uint_as_float(q.x & 0xffff0000u);
            a[2] = __uint_as_float(q.y << 16);  a[3] = __uint_as_float(q.y & 0xffff0000u);
            a[4] = __uint_as_float(q.z << 16);  a[5] = __uint_as_float(q.z & 0xffff0000u);
            a[6] = __uint_as_float(q.w << 16);  a[7] = __uint_as_float(q.w & 0xffff0000u);
        } else {
            #pragma unroll
            for (int j = 0; j < 8; ++j) a[j] = 0.0f;
        }
        int k = g;
        for (; k + 12 < cnt; k += 16) {   // 4 edges in flight per lane
            const int s0 = nb[k], s1 = nb[k + 4], s2 = nb[k + 8], s3 = nb[k + 12];
            const uint4 q0 = *(const uint4*)&tab[(size_t)s0 * 32 + c * 8];
            const uint4 q1 = *(const uint4*)&tab[(size_t)s1 * 32 + c * 8];
            const uint4 q2 = *(const uint4*)&tab[(size_t)s2 * 32 + c * 8];
            const uint4 q3 = *(const uint4*)&tab[(size_t)s3 * 32 + c * 8];
            ACC8(q0); ACC8(q1); ACC8(q2); ACC8(q3);
        }
        for (; k < cnt; k += 4) {
            const uint4 q = *(const uint4*)&tab[(size_t)nb[k] * 32 + c * 8];
            ACC8(q);
        }
        // reduce the 4 edge-groups (lanes differing in tid bits 2,3)
        #pragma unroll
        for (int j = 0; j < 8; ++j) {
            a[j] += __shfl_xor(a[j], 4);
            a[j] += __shfl_xor(a[j], 8);
        }
        if (g == 0) {
            #pragma unroll
            for (int j = 0; j < 8; ++j) {
                const int col = s * 32 + c * 8 + j;
                h1s[nloc][col] = fmaxf(fmaf(a[j], inv, ba[col]), 0.0f);
            }
        }
    }

    // ---- phase 2: y2 = h1 @ W2 in four 16-col quarters ----
    for (int q = 0; q < 4; ++q) {
        __syncthreads();              // h1s ready / previous quarter consumed
        #pragma unroll
        for (int i = 0; i < 2; ++i) {
            const int f = tid + i * 256;      // 512 float4 slots = 128 rows x 4
            const int kk = f >> 2;            // 0..127
            const int c4 = f & 3;             // 0..3
            const float4 w = *(const float4*)&W2[kk * DOUT + q * 16 + c4 * 4];
            w2s[c4 * 4 + 0][kk] = w.x;
            w2s[c4 * 4 + 1][kk] = w.y;
            w2s[c4 * 4 + 2][kk] = w.z;
            w2s[c4 * 4 + 3][kk] = w.w;
        }
        __syncthreads();
        float acc0 = 0.0f;
        #pragma unroll
        for (int kk = 0; kk < D; kk += 4) {
            const float4 hv = *(const float4*)&h1s[nloc][kk];
            const float4 w0 = *(const float4*)&w2s[sub][kk];
            acc0 = fmaf(hv.x, w0.x, fmaf(hv.y, w0.y, fmaf(hv.z, w0.z, fmaf(hv.w, w0.w, acc0))));
        }
        y2[(size_t)node * DOUT + q * 16 + sub] = f32_to_bf16(acc0);
    }
}

// out = rownorm(mean_agg(y2) + b2): 8 lanes/node, 8-deep load pipeline
__global__ void gather2_kernel(const uint4* __restrict__ y2, const int* __restrict__ rowstart,
                               const unsigned short* __restrict__ ebuf,
                               const float* __restrict__ b2, float* __restrict__ out) {
    const int gid = blockIdx.x * blockDim.x + threadIdx.x;
    const int node = gid >> 3;
    const int sub = gid & 7;
    if (node >= NNODES) return;
    const int beg = rowstart[node];
    const int cnt = rowstart[node + 1] - beg;
    float a[8];
    {
        const uint4 q = y2[(size_t)node * 8 + sub];
        a[0] = __uint_as_float(q.x << 16);  a[1] = __uint_as_float(q.x & 0xffff0000u);
        a[2] = __uint_as_float(q.y << 16);  a[3] = __uint_as_float(q.y & 0xffff0000u);
        a[4] = __uint_as_float(q.z << 16);  a[5] = __uint_as_float(q.z & 0xffff0000u);
        a[6] = __uint_as_float(q.w << 16);  a[7] = __uint_as_float(q.w & 0xffff0000u);
    }
    const unsigned short* nb = ebuf + beg;
    int k = 0;
    for (; k + 8 <= cnt; k += 8) {
        int s[8];
        #pragma unroll
        for (int i = 0; i < 8; ++i) s[i] = nb[k + i];
        uint4 q[8];
        #pragma unroll
        for (int i = 0; i < 8; ++i) q[i] = y2[(size_t)s[i] * 8 + sub];
        #pragma unroll
        for (int i = 0; i < 8; ++i) ACC8(q[i]);
    }
    for (; k < cnt; ++k) {
        const uint4 q = y2[(size_t)nb[k] * 8 + sub];
        ACC8(q);
    }
    const float inv = 1.0f / (float)(cnt + 1);
    float v[8];
    float ss = 0.0f;
    #pragma unroll
    for (int j = 0; j < 8; ++j) {
        v[j] = fmaf(a[j], inv, b2[sub * 8 + j]);
        ss = fmaf(v[j], v[j], ss);
    }
    ss += __shfl_xor(ss, 1);
    ss += __shfl_xor(ss, 2);
    ss += __shfl_xor(ss, 4);
    const float scale = 1.0f / fmaxf(sqrtf(ss), 1e-12f);
    float o[8];
    #pragma unroll
    for (int j = 0; j < 8; ++j) o[j] = v[j] * scale;
    float* dst = &out[(size_t)node * DOUT + sub * 8];
    *(float4*)&dst[0] = *(const float4*)&o[0];
    *(float4*)&dst[4] = *(const float4*)&o[4];
}

// ---------------------------------------------------------------------------
extern "C" void kernel_launch(void* const* d_in, const int* in_sizes, int n_in,
                              void* d_out, int out_size, void* d_ws, size_t ws_size,
                              hipStream_t stream) {
    const float* x    = (const float*)d_in[0];
    const int*   ei   = (const int*)d_in[1];
    const float* Wpre = (const float*)d_in[2];
    const float* bpre = (const float*)d_in[3];
    const float* W1   = (const float*)d_in[4];
    const float* b1   = (const float*)d_in[5];
    const float* W2   = (const float*)d_in[6];
    const float* b2   = (const float*)d_in[7];
    float* out = (float*)d_out;

    // workspace layout (~25.5 MB)
    char* ws = (char*)d_ws;
    unsigned short* y1   = (unsigned short*)ws;                 // [4][N][32] bf16 = 12.8 MB
    unsigned short* y2   = (unsigned short*)(ws + 12800000);    // [N*64]  bf16 = 6.4 MB
    int* deg             = (int*)(ws + 19200000);               // [50176]
    int* rowstart        = (int*)(ws + 19400704);               // [50176] (N+1 used)
    unsigned short* ebuf = (unsigned short*)(ws + 19601408);    // [E] ushort = 1.6 MB
    unsigned int* bins   = (unsigned int*)(ws + 21201408);      // [NBUCK*BCAP] = 4.0 MB
    int* bcursor         = (int*)(ws + 25205248);               // [NBUCK]
    int* excl            = (int*)(ws + 25207296);               // [SCAN_BLOCKS*256]
    int* partials        = (int*)(ws + 25408000);               // [256]
    unsigned short* waT  = (unsigned short*)(ws + 25409024);    // [128*128] bf16 = 32 KB
    float* ba            = (float*)(ws + 25441792);             // [128]

    // binned CSR build (bcursor = per-bucket counts, zeroed each launch)
    hipMemsetAsync(bcursor, 0, NBUCK * sizeof(int), stream);
    bin_kernel<<<(NEDGES + CH - 1) / CH, 256, 0, stream>>>(ei, bcursor, bins);
    count_kernel<<<NBUCK, 256, 0, stream>>>(bins, bcursor, deg);
    scan_part1<<<SCAN_BLOCKS, 256, 0, stream>>>(deg, excl, partials);
    scan_part3<<<SCAN_BLOCKS, 256, 0, stream>>>(excl, partials, rowstart);
    place_kernel<<<NBUCK, 256, 0, stream>>>(bins, bcursor, rowstart, ebuf);

    // folded weights (waT emitted transposed bf16 for MFMA B-operand)
    combine_w_kernel<<<D + 1, D, 0, stream>>>(Wpre, bpre, W1, b1, waT, ba);

    // layer 1: y1 = bf16(x @ Wa) via MFMA, slice-major
    gemm_y1_mfma<<<(NNODES + 63) / 64, 256, 0, stream>>>(x, waT, y1);

    // fused: h1 = relu(mean_agg(y1)+ba) in LDS (column-sliced); y2 = bf16(h1 @ W2)
    gather1_gemm2_kernel<<<NNODES / NPB, 256, 0, stream>>>(
        y1, rowstart, ebuf, ba, W2, y2);

    // layer 2 aggregate + normalize
    gather2_kernel<<<(NNODES * 8 + 255) / 256, 256, 0, stream>>>(
        (const uint4*)y2, rowstart, ebuf, b2, out);
}

// Round 11
// 191.354 us; speedup vs baseline: 1.0921x; 1.0921x over previous
//
#include <hip/hip_runtime.h>
#include <hip/hip_bf16.h>

#define NNODES 50000
#define NEDGES 800000
#define D 128
#define DOUT 64
#define NPB 16            // nodes per block in fused gather1+gemm2

// binned CSR build
#define BSHIFT 7
#define BMASK 127
#define NBUCK 391         // ceil(50000/128)
#define BCAP 2560         // bucket capacity (mean 2048, sigma~45 -> >11 sigma)
#define CH 2048           // edges per bin block

typedef unsigned short ushort8 __attribute__((ext_vector_type(8)));
typedef short bf16x8 __attribute__((ext_vector_type(8)));
typedef float f32x4 __attribute__((ext_vector_type(4)));

__device__ inline unsigned short f32_to_bf16(float f) {
    unsigned u = __float_as_uint(f);
    u = (u + 0x7fffu + ((u >> 16) & 1u)) >> 16;   // round-to-nearest-even
    return (unsigned short)u;
}

// ---------------------------------------------------------------------------
// waT[c][k] = bf16((Wpre @ W1)[k][c]);  ba = bpre @ W1 + b1 (f32)
__global__ void combine_w_kernel(const float* __restrict__ Wpre, const float* __restrict__ bpre,
                                 const float* __restrict__ W1, const float* __restrict__ b1,
                                 unsigned short* __restrict__ waT, float* __restrict__ ba) {
    const int j = threadIdx.x;
    const int i = blockIdx.x;
    if (i < D) {
        float s = 0.0f;
        for (int k = 0; k < D; ++k) s = fmaf(Wpre[i * D + k], W1[k * D + j], s);
        waT[j * D + i] = f32_to_bf16(s);     // transposed store
    } else {
        float s = b1[j];
        for (int k = 0; k < D; ++k) s = fmaf(bpre[k], W1[k * D + j], s);
        ba[j] = s;
    }
}

// --- binned CSR build ------------------------------------------------------
// bcursor[b] = COUNT in bucket b (zeroed by memset each launch).
__global__ void bin_kernel(const int* __restrict__ ei, int* __restrict__ bcursor,
                           unsigned int* __restrict__ bins) {
    __shared__ int cnt[NBUCK];
    __shared__ int base[NBUCK];
    const int tid = threadIdx.x;
    const int e0 = blockIdx.x * CH;

    for (int i = tid; i < NBUCK; i += 256) cnt[i] = 0;
    __syncthreads();

    int src[8], dstl[8], nb[8];
    #pragma unroll
    for (int i = 0; i < 8; ++i) {
        const int e = e0 + i * 256 + tid;
        if (e < NEDGES) {
            src[i] = ei[e];
            const int d = ei[NEDGES + e];
            dstl[i] = d & BMASK;
            nb[i] = d >> BSHIFT;
        } else {
            nb[i] = -1;
        }
    }
    #pragma unroll
    for (int i = 0; i < 8; ++i)
        if (nb[i] >= 0) atomicAdd(&cnt[nb[i]], 1);
    __syncthreads();

    for (int b = tid; b < NBUCK; b += 256) {
        base[b] = (cnt[b] > 0) ? (b * BCAP + atomicAdd(&bcursor[b], cnt[b])) : 0;
        cnt[b] = 0;   // reuse as local offset
    }
    __syncthreads();

    #pragma unroll
    for (int i = 0; i < 8; ++i) {
        if (nb[i] >= 0) {
            const int off = atomicAdd(&cnt[nb[i]], 1);
            const int pos = base[nb[i]] + off;
            if (pos < (nb[i] + 1) * BCAP)
                bins[pos] = ((unsigned)src[i] << BSHIFT) | (unsigned)dstl[i];
        }
    }
}

// exclusive scan of the 391 bucket counts -> bucketbase (one block)
__global__ void bucketscan_kernel(const int* __restrict__ bcursor,
                                  int* __restrict__ bucketbase) {
    __shared__ int sm[512];
    const int t = threadIdx.x;
    int v = 0;
    if (t < NBUCK) {
        v = bcursor[t];
        if (v > BCAP) v = BCAP;
    }
    sm[t] = v;
    __syncthreads();
    #pragma unroll
    for (int off = 1; off < 512; off <<= 1) {
        const int cur = sm[t];
        const int add = (t >= off) ? sm[t - off] : 0;
        __syncthreads();
        sm[t] = cur + add;
        __syncthreads();
    }
    if (t < NBUCK) bucketbase[t] = sm[t] - v;
}

// fused: per-bucket degree histogram -> local 128-scan -> rowstart + ebuf place
__global__ void place2_kernel(const unsigned int* __restrict__ bins,
                              const int* __restrict__ bcursor,
                              const int* __restrict__ bucketbase,
                              int* __restrict__ rowstart,
                              unsigned short* __restrict__ ebuf) {
    __shared__ int cnt[128];
    __shared__ int sc[128];
    __shared__ int lcur[128];
    const int b = blockIdx.x;
    const int tid = threadIdx.x;
    if (tid < 128) cnt[tid] = 0;
    __syncthreads();

    int n = bcursor[b];
    if (n > BCAP) n = BCAP;
    const unsigned int* p = bins + (size_t)b * BCAP;

    for (int i = tid; i < n; i += 256) atomicAdd(&cnt[p[i] & BMASK], 1);
    __syncthreads();

    if (tid < 128) sc[tid] = cnt[tid];
    __syncthreads();
    #pragma unroll
    for (int off = 1; off < 128; off <<= 1) {
        int cur = 0, add = 0;
        if (tid < 128) {
            cur = sc[tid];
            if (tid >= off) add = sc[tid - off];
        }
        __syncthreads();
        if (tid < 128) sc[tid] = cur + add;
        __syncthreads();
    }
    if (tid < 128) {
        const int rs = bucketbase[b] + sc[tid] - cnt[tid];   // exclusive
        const int node = b * 128 + tid;
        if (node <= NNODES) rowstart[node] = rs;             // node==NNODES -> total
        lcur[tid] = rs;
    }
    __syncthreads();

    for (int i = tid; i < n; i += 256) {
        const unsigned v = p[i];
        const int pos = atomicAdd(&lcur[v & BMASK], 1);
        ebuf[pos] = (unsigned short)(v >> BSHIFT);
    }
}

// ---------------------------------------------------------------------------
// y1 = bf16(x @ Wa) via MFMA. Block: 256 thr = 4 waves, tile 64 rows x 128 cols.
__global__ void __launch_bounds__(256) gemm_y1_mfma(const float* __restrict__ x,
                                                    const unsigned short* __restrict__ waT,
                                                    unsigned short* __restrict__ y1) {
    __shared__ unsigned short xs[64][136];
    __shared__ unsigned short wsm[128][136];
    const int tid = threadIdx.x;
    const int rbase = blockIdx.x * 64;

    #pragma unroll
    for (int i = 0; i < 8; ++i) {
        const int f = tid + i * 256;
        const int r = f >> 4;              // 0..127
        const int c8 = f & 15;
        *(ushort8*)&wsm[r][c8 * 8] = *(const ushort8*)&waT[r * D + c8 * 8];
    }
    #pragma unroll
    for (int i = 0; i < 4; ++i) {
        const int f = tid + i * 256;
        const int r = f >> 4;              // 0..63
        const int c8 = f & 15;
        int rg = rbase + r;
        if (rg > NNODES - 1) rg = NNODES - 1;
        const float4 v0 = *(const float4*)&x[(size_t)rg * D + c8 * 8];
        const float4 v1 = *(const float4*)&x[(size_t)rg * D + c8 * 8 + 4];
        ushort8 o;
        o[0] = f32_to_bf16(v0.x); o[1] = f32_to_bf16(v0.y);
        o[2] = f32_to_bf16(v0.z); o[3] = f32_to_bf16(v0.w);
        o[4] = f32_to_bf16(v1.x); o[5] = f32_to_bf16(v1.y);
        o[6] = f32_to_bf16(v1.z); o[7] = f32_to_bf16(v1.w);
        *(ushort8*)&xs[r][c8 * 8] = o;
    }
    __syncthreads();

    const int lane = tid & 63;
    const int wv = tid >> 6;          // wave -> rows wv*16..+15
    const int r16 = lane & 15;
    const int kg = lane >> 4;         // 0..3

    f32x4 acc[8];
    #pragma unroll
    for (int ct = 0; ct < 8; ++ct) acc[ct] = (f32x4){0.f, 0.f, 0.f, 0.f};

    #pragma unroll
    for (int kq = 0; kq < 4; ++kq) {
        const int ko = kq * 32 + kg * 8;
        const bf16x8 a = *(const bf16x8*)&xs[wv * 16 + r16][ko];
        #pragma unroll
        for (int ct = 0; ct < 8; ++ct) {
            const bf16x8 b = *(const bf16x8*)&wsm[ct * 16 + r16][ko];
            acc[ct] = __builtin_amdgcn_mfma_f32_16x16x32_bf16(a, b, acc[ct], 0, 0, 0);
        }
    }

    #pragma unroll
    for (int ct = 0; ct < 8; ++ct) {
        #pragma unroll
        for (int reg = 0; reg < 4; ++reg) {
            const int row = rbase + wv * 16 + kg * 4 + reg;
            if (row < NNODES)
                y1[(size_t)row * D + ct * 16 + r16] = f32_to_bf16(acc[ct][reg]);
        }
    }
}

// ---------------------------------------------------------------------------
#define ACC8(q)                                                        \
    do {                                                               \
        a[0] += __uint_as_float((q).x << 16);                          \
        a[1] += __uint_as_float((q).x & 0xffff0000u);                  \
        a[2] += __uint_as_float((q).y << 16);                          \
        a[3] += __uint_as_float((q).y & 0xffff0000u);                  \
        a[4] += __uint_as_float((q).z << 16);                          \
        a[5] += __uint_as_float((q).z & 0xffff0000u);                  \
        a[6] += __uint_as_float((q).w << 16);                          \
        a[7] += __uint_as_float((q).w & 0xffff0000u);                  \
    } while (0)

// Fused: h1 = relu(mean_agg(y1)+ba) -> LDS (f32); y2 = bf16(h1 @ W2)
// (round-8 proven form: 49.0us, VGPR 32, occ ~65%)
__global__ void gather1_gemm2_kernel(const uint4* __restrict__ y1,
                                     const int* __restrict__ rowstart,
                                     const unsigned short* __restrict__ ebuf,
                                     const float* __restrict__ ba,
                                     const float* __restrict__ W2,
                                     unsigned short* __restrict__ y2) {
    __shared__ float h1s[NPB][132];   // reads are nloc-broadcast: conflict-free
    __shared__ float w2s[16][132];    // float4 reads: 2-way aliasing = free (m136)
    const int tid = threadIdx.x;
    const int nloc = tid >> 4;        // 0..15
    const int sub = tid & 15;         // 0..15
    const int node = blockIdx.x * NPB + nloc;

    // ---- phase 1: gather + mean + bias + relu -> h1s (f32) ----
    const int beg = rowstart[node];
    const int cnt = rowstart[node + 1] - beg;
    float a[8];
    {
        const uint4 q = y1[(size_t)node * 16 + sub];   // self loop
        a[0] = __uint_as_float(q.x << 16);  a[1] = __uint_as_float(q.x & 0xffff0000u);
        a[2] = __uint_as_float(q.y << 16);  a[3] = __uint_as_float(q.y & 0xffff0000u);
        a[4] = __uint_as_float(q.z << 16);  a[5] = __uint_as_float(q.z & 0xffff0000u);
        a[6] = __uint_as_float(q.w << 16);  a[7] = __uint_as_float(q.w & 0xffff0000u);
    }
    const unsigned short* nb = ebuf + beg;
    int k = 0;
    for (; k + 4 <= cnt; k += 4) {
        const int s0 = nb[k], s1 = nb[k + 1], s2 = nb[k + 2], s3 = nb[k + 3];
        const uint4 q0 = y1[(size_t)s0 * 16 + sub];
        const uint4 q1 = y1[(size_t)s1 * 16 + sub];
        const uint4 q2 = y1[(size_t)s2 * 16 + sub];
        const uint4 q3 = y1[(size_t)s3 * 16 + sub];
        ACC8(q0); ACC8(q1); ACC8(q2); ACC8(q3);
    }
    for (; k < cnt; ++k) {
        const uint4 q = y1[(size_t)nb[k] * 16 + sub];
        ACC8(q);
    }
    const float inv = 1.0f / (float)(cnt + 1);
    #pragma unroll
    for (int j = 0; j < 8; ++j)
        h1s[nloc][sub * 8 + j] = fmaxf(fmaf(a[j], inv, ba[sub * 8 + j]), 0.0f);

    // ---- phase 2: y2 = h1 @ W2 in four 16-col quarters ----
    for (int q = 0; q < 4; ++q) {
        __syncthreads();              // h1s ready / previous quarter consumed
        #pragma unroll
        for (int i = 0; i < 2; ++i) {
            const int f = tid + i * 256;      // 512 float4 slots = 128 rows x 4
            const int kk = f >> 2;            // 0..127
            const int c4 = f & 3;             // 0..3
            const float4 w = *(const float4*)&W2[kk * DOUT + q * 16 + c4 * 4];
            w2s[c4 * 4 + 0][kk] = w.x;
            w2s[c4 * 4 + 1][kk] = w.y;
            w2s[c4 * 4 + 2][kk] = w.z;
            w2s[c4 * 4 + 3][kk] = w.w;
        }
        __syncthreads();
        float acc0 = 0.0f;
        #pragma unroll
        for (int kk = 0; kk < D; kk += 4) {
            const float4 hv = *(const float4*)&h1s[nloc][kk];
            const float4 w0 = *(const float4*)&w2s[sub][kk];
            acc0 = fmaf(hv.x, w0.x, fmaf(hv.y, w0.y, fmaf(hv.z, w0.z, fmaf(hv.w, w0.w, acc0))));
        }
        y2[(size_t)node * DOUT + q * 16 + sub] = f32_to_bf16(acc0);
    }
}

// out = rownorm(mean_agg(y2) + b2): 8 lanes/node, 8-deep load pipeline
__global__ void gather2_kernel(const uint4* __restrict__ y2, const int* __restrict__ rowstart,
                               const unsigned short* __restrict__ ebuf,
                               const float* __restrict__ b2, float* __restrict__ out) {
    const int gid = blockIdx.x * blockDim.x + threadIdx.x;
    const int node = gid >> 3;
    const int sub = gid & 7;
    if (node >= NNODES) return;
    const int beg = rowstart[node];
    const int cnt = rowstart[node + 1] - beg;
    float a[8];
    {
        const uint4 q = y2[(size_t)node * 8 + sub];
        a[0] = __uint_as_float(q.x << 16);  a[1] = __uint_as_float(q.x & 0xffff0000u);
        a[2] = __uint_as_float(q.y << 16);  a[3] = __uint_as_float(q.y & 0xffff0000u);
        a[4] = __uint_as_float(q.z << 16);  a[5] = __uint_as_float(q.z & 0xffff0000u);
        a[6] = __uint_as_float(q.w << 16);  a[7] = __uint_as_float(q.w & 0xffff0000u);
    }
    const unsigned short* nb = ebuf + beg;
    int k = 0;
    for (; k + 8 <= cnt; k += 8) {
        int s[8];
        #pragma unroll
        for (int i = 0; i < 8; ++i) s[i] = nb[k + i];
        uint4 q[8];
        #pragma unroll
        for (int i = 0; i < 8; ++i) q[i] = y2[(size_t)s[i] * 8 + sub];
        #pragma unroll
        for (int i = 0; i < 8; ++i) ACC8(q[i]);
    }
    for (; k < cnt; ++k) {
        const uint4 q = y2[(size_t)nb[k] * 8 + sub];
        ACC8(q);
    }
    const float inv = 1.0f / (float)(cnt + 1);
    float v[8];
    float ss = 0.0f;
    #pragma unroll
    for (int j = 0; j < 8; ++j) {
        v[j] = fmaf(a[j], inv, b2[sub * 8 + j]);
        ss = fmaf(v[j], v[j], ss);
    }
    ss += __shfl_xor(ss, 1);
    ss += __shfl_xor(ss, 2);
    ss += __shfl_xor(ss, 4);
    const float scale = 1.0f / fmaxf(sqrtf(ss), 1e-12f);
    float o[8];
    #pragma unroll
    for (int j = 0; j < 8; ++j) o[j] = v[j] * scale;
    float* dst = &out[(size_t)node * DOUT + sub * 8];
    *(float4*)&dst[0] = *(const float4*)&o[0];
    *(float4*)&dst[4] = *(const float4*)&o[4];
}

// ---------------------------------------------------------------------------
extern "C" void kernel_launch(void* const* d_in, const int* in_sizes, int n_in,
                              void* d_out, int out_size, void* d_ws, size_t ws_size,
                              hipStream_t stream) {
    const float* x    = (const float*)d_in[0];
    const int*   ei   = (const int*)d_in[1];
    const float* Wpre = (const float*)d_in[2];
    const float* bpre = (const float*)d_in[3];
    const float* W1   = (const float*)d_in[4];
    const float* b1   = (const float*)d_in[5];
    const float* W2   = (const float*)d_in[6];
    const float* b2   = (const float*)d_in[7];
    float* out = (float*)d_out;

    // workspace layout (~25.1 MB)
    char* ws = (char*)d_ws;
    unsigned short* y1   = (unsigned short*)ws;                 // [N*128] bf16 = 12.8 MB
    unsigned short* y2   = (unsigned short*)(ws + 12800000);    // [N*64]  bf16 = 6.4 MB
    int* rowstart        = (int*)(ws + 19200000);               // [50176] (N+1 used)
    unsigned short* ebuf = (unsigned short*)(ws + 19400704);    // [E] ushort = 1.6 MB
    unsigned int* bins   = (unsigned int*)(ws + 21000704);      // [NBUCK*BCAP] = 4.0 MB
    int* bcursor         = (int*)(ws + 25004544);               // [NBUCK]
    int* bucketbase      = (int*)(ws + 25006592);               // [NBUCK]
    unsigned short* waT  = (unsigned short*)(ws + 25008640);    // [128*128] bf16 = 32 KB
    float* ba            = (float*)(ws + 25041408);             // [128]

    // binned CSR build: bin -> bucketscan -> fused place2 (8 dispatches total)
    hipMemsetAsync(bcursor, 0, NBUCK * sizeof(int), stream);
    bin_kernel<<<(NEDGES + CH - 1) / CH, 256, 0, stream>>>(ei, bcursor, bins);
    bucketscan_kernel<<<1, 512, 0, stream>>>(bcursor, bucketbase);
    place2_kernel<<<NBUCK, 256, 0, stream>>>(bins, bcursor, bucketbase, rowstart, ebuf);

    // folded weights (waT emitted transposed bf16 for MFMA B-operand)
    combine_w_kernel<<<D + 1, D, 0, stream>>>(Wpre, bpre, W1, b1, waT, ba);

    // layer 1: y1 = bf16(x @ Wa) via MFMA
    gemm_y1_mfma<<<(NNODES + 63) / 64, 256, 0, stream>>>(x, waT, y1);

    // fused: h1 = relu(mean_agg(y1)+ba) in LDS; y2 = bf16(h1 @ W2)
    gather1_gemm2_kernel<<<NNODES / NPB, 256, 0, stream>>>(
        (const uint4*)y1, rowstart, ebuf, ba, W2, y2);

    // layer 2 aggregate + normalize
    gather2_kernel<<<(NNODES * 8 + 255) / 256, 256, 0, stream>>>(
        (const uint4*)y2, rowstart, ebuf, b2, out);
}